// Round 4
// baseline (272.358 us; speedup 1.0000x reference)
//
#include <hip/hip_runtime.h>

#define NOUT 7
#define NROI 512
#define NCH 256
#define BINS (NOUT * NOUT)        // 49
#define ROI_ELEMS (NCH * BINS)    // 12544
#define G 4                       // channels per block
#define NGROUP (NCH / G)          // 64 channel groups
#define WINCAP 1152               // floats per channel window (proven max need 1143)

__global__ __launch_bounds__(256) void roi_pool_kernel(
    const float* __restrict__ x2,
    const float* __restrict__ x3,
    const float* __restrict__ x4,
    const float* __restrict__ x5,
    const float* __restrict__ boxes,
    float* __restrict__ out)
{
    const int r  = blockIdx.x;   // roi 0..511
    const int cg = blockIdx.y;   // channel group 0..63
    const int t  = threadIdx.x;  // 0..255

    // Per-channel staged windows (row-major, stride ldsw, forced odd to
    // destagger banks). 4*1152*4B = 18.4 KB -> 8 blocks/CU.
    __shared__ float win[G * WINCAP];
    // Descriptors:
    //  sdy[j] = { asfloat(rowrel_j * ldsw), fy, 0.25*valid_y, 0 }
    //  sdx[k] = { asfloat(colrel_k),        fx, valid_x,      0 }
    __shared__ float4 sdy[14];
    __shared__ float4 sdx[14];
    __shared__ int sgeo[8];          // nrows, span, ldsw, lpr-1, shift, W, HW
    __shared__ const float* sbase;   // feat + b*C*H*W + y0min*W + x0min

    if (t < 32) {
        const float bx1 = boxes[4 * r + 0];
        const float by1 = boxes[4 * r + 1];
        const float bx2 = boxes[4 * r + 2];
        const float by2 = boxes[4 * r + 3];
        const float sz  = sqrtf((bx2 - bx1) * (by2 - by1));
        float lvlf = floorf(4.0f + log2f(sz / 224.0f + 1e-8f));
        lvlf = fminf(fmaxf(lvlf, 2.0f), 5.0f);
        const int level = (int)lvlf - 2;

        int H, W; float scale; const float* feat;
        if (level == 0)      { H = 200; W = 304; scale = 0.25f;    feat = x2; }
        else if (level == 1) { H = 100; W = 152; scale = 0.125f;   feat = x3; }
        else if (level == 2) { H = 50;  W = 76;  scale = 0.0625f;  feat = x4; }
        else                 { H = 25;  W = 38;  scale = 0.03125f; feat = x5; }

        const float X1 = bx1 * scale - 0.5f;
        const float Y1 = by1 * scale - 0.5f;
        const float X2 = bx2 * scale - 0.5f;
        const float Y2 = by2 * scale - 0.5f;
        const float bw = (X2 - X1) * (1.0f / NOUT);
        const float bh = (Y2 - Y1) * (1.0f / NOUT);

        // i0 of sample g (normalized so i1 = i0+1 always; exact-match of R3 math)
        auto i0_of = [](float c, int size) -> int {
            c = fminf(fmaxf(c, 0.0f), (float)(size - 1));
            int i0 = (int)floorf(c);
            return min(i0, size - 2);
        };
        // samples are monotonic in j (bh,bw > 0), so min/max are samples 0/13
        const float g0 = 0.25f, g13 = 0.25f + 0.5f * 13.0f;
        const int y0min = i0_of(Y1 + g0 * bh, H);
        const int y0max = i0_of(Y1 + g13 * bh, H);
        const int x0min = i0_of(X1 + g0 * bw, W);
        const int x0max = i0_of(X1 + g13 * bw, W);
        const int nrows = y0max - y0min + 2;   // rows staged
        const int span  = x0max - x0min + 2;   // cols staged (<= 127)
        const int ldsw  = span | 1;            // odd stride, bank destagger
        int lpr = 8;                           // lanes per row chunk (pow2 >= span)
        while (lpr < span && lpr < 128) lpr <<= 1;
        const int shift = 31 - __clz(lpr);

        if (t < 14) {
            const float g = 0.25f + 0.5f * (float)t;
            float c = Y1 + g * bh;
            const bool valid = (c >= -1.0f) && (c <= (float)H);
            c = fminf(fmaxf(c, 0.0f), (float)(H - 1));
            int i0 = min((int)floorf(c), H - 2);
            sdy[t] = make_float4(__int_as_float((i0 - y0min) * ldsw),
                                 c - (float)i0,
                                 valid ? 0.25f : 0.0f, 0.0f);
        } else if (t >= 16 && t < 30) {
            const int k = t - 16;
            const float g = 0.25f + 0.5f * (float)k;
            float c = X1 + g * bw;
            const bool valid = (c >= -1.0f) && (c <= (float)W);
            c = fminf(fmaxf(c, 0.0f), (float)(W - 1));
            int i0 = min((int)floorf(c), W - 2);
            sdx[k] = make_float4(__int_as_float(i0 - x0min),
                                 c - (float)i0,
                                 valid ? 1.0f : 0.0f, 0.0f);
        } else if (t == 31) {
            sgeo[0] = nrows;
            sgeo[1] = span;
            sgeo[2] = ldsw;
            sgeo[3] = lpr - 1;
            sgeo[4] = shift;
            sgeo[5] = W;
            sgeo[6] = H * W;
            const int b = r >> 8;
            sbase = feat + (size_t)b * NCH * H * W + (size_t)(y0min * W + x0min);
        }
    }
    __syncthreads();

    const int nrows = sgeo[0];
    const int span  = sgeo[1];
    const int ldsw  = sgeo[2];
    const int lprm1 = sgeo[3];
    const int shift = sgeo[4];
    const int W     = sgeo[5];
    const int HW    = sgeo[6];
    const float* const base = sbase;
    const int c0 = cg * G;

    // ---- stage G channel windows, coalesced row segments ----
    const int rpi = 256 >> shift;                 // rows per iteration
    const int sub = t >> shift;                   // my row within chunk
    const int col = min(t & lprm1, span - 1);     // clamped col (redundant lanes
                                                  // re-read last col: same line)
    #pragma unroll
    for (int c = 0; c < G; ++c) {
        const float* src = base + (size_t)(c0 + c) * HW;
        float* dst = win + c * WINCAP;
        for (int rb = 0; rb < nrows; rb += rpi) {
            const int row = min(rb + sub, nrows - 1);
            dst[row * ldsw + col] = src[row * W + col];
        }
    }
    __syncthreads();

    // ---- compute: 4 channels x 49 bins, gathers from LDS ----
    if (t < G * BINS) {
        const int cl  = t / BINS;
        const int bin = t - cl * BINS;
        const int ph  = bin / NOUT;
        const int pw  = bin - ph * NOUT;

        const float4 dy0 = sdy[ph * 2 + 0];
        const float4 dy1 = sdy[ph * 2 + 1];
        const float4 dx0 = sdx[pw * 2 + 0];
        const float4 dx1 = sdx[pw * 2 + 1];
        const float* const w0 = win + cl * WINCAP;

        float acc = 0.0f;
        #pragma unroll
        for (int sy = 0; sy < 2; ++sy) {
            const float4 dy = sy ? dy1 : dy0;
            const float* const rowp = w0 + __float_as_int(dy.x);
            const float fy = dy.y;
            const float wy = dy.z;
            #pragma unroll
            for (int sx = 0; sx < 2; ++sx) {
                const float4 dx = sx ? dx1 : dx0;
                const int cxi  = __float_as_int(dx.x);
                const float fx = dx.y;
                const float wx = dx.z;
                const float v00 = rowp[cxi];
                const float v01 = rowp[cxi + 1];
                const float v10 = rowp[cxi + ldsw];
                const float v11 = rowp[cxi + ldsw + 1];
                const float top = v00 + (v01 - v00) * fx;
                const float bot = v10 + (v11 - v10) * fx;
                acc += wy * wx * (top + (bot - top) * fy);
            }
        }
        out[(size_t)r * ROI_ELEMS + (size_t)c0 * BINS + t] = acc;
    }
}

extern "C" void kernel_launch(void* const* d_in, const int* in_sizes, int n_in,
                              void* d_out, int out_size, void* d_ws, size_t ws_size,
                              hipStream_t stream) {
    const float* x2    = (const float*)d_in[0];
    const float* x3    = (const float*)d_in[1];
    const float* x4    = (const float*)d_in[2];
    const float* x5    = (const float*)d_in[3];
    const float* boxes = (const float*)d_in[4];
    float* out = (float*)d_out;

    dim3 grid(NROI, NGROUP);
    roi_pool_kernel<<<grid, 256, 0, stream>>>(x2, x3, x4, x5, boxes, out);
}